// Round 8
// baseline (295.306 us; speedup 1.0000x reference)
//
#include <hip/hip_runtime.h>
#include <hip/hip_bf16.h>

#define D_FEAT 256
#define EPS 1e-12f

// Build CSR row_ptr from sorted COO row array.
__global__ void build_row_ptr_kernel(const int* __restrict__ row,
                                     int* __restrict__ row_ptr,
                                     int E, int N) {
    int e = blockIdx.x * blockDim.x + threadIdx.x;
    if (e > E) return;
    int curr = (e == E) ? N : row[e];
    int prev = (e == 0) ? -1 : row[e - 1];
    for (int r = prev + 1; r <= curr; ++r) row_ptr[r] = e;
}

// Quantize fp32 rows -> biased uint8 (q = round(v/scale)+128) + per-row scale.
// One wave per row; lane l owns dims [4l, 4l+4).
__global__ __launch_bounds__(256) void quant_rows_kernel(
    const float* __restrict__ in,
    unsigned char* __restrict__ q,
    float* __restrict__ s,
    int n_rows)
{
    const int wave = threadIdx.x >> 6, lane = threadIdx.x & 63;
    const int r = blockIdx.x * 4 + wave;
    if (r >= n_rows) return;
    const long idx = (long)r * 64 + lane;
    const float4 f = ((const float4*)in)[idx];
    float m = fmaxf(fmaxf(fabsf(f.x), fabsf(f.y)), fmaxf(fabsf(f.z), fabsf(f.w)));
    #pragma unroll
    for (int off = 32; off; off >>= 1) m = fmaxf(m, __shfl_xor(m, off));
    const float mg  = fmaxf(m, 1e-30f);
    const float inv = 127.0f / mg;
    const unsigned int u0 = (unsigned int)(int)rintf(fmaf(f.x, inv, 128.0f));
    const unsigned int u1 = (unsigned int)(int)rintf(fmaf(f.y, inv, 128.0f));
    const unsigned int u2 = (unsigned int)(int)rintf(fmaf(f.z, inv, 128.0f));
    const unsigned int u3 = (unsigned int)(int)rintf(fmaf(f.w, inv, 128.0f));
    ((unsigned int*)q)[idx] = u0 | (u1 << 8) | (u2 << 16) | (u3 << 24);
    if (lane == 0) s[r] = mg * (1.0f / 127.0f);
}

// Fused SpMM (CSR, int8 features + per-row scale) + L2 normalize.
// One wave per output row. Edge metadata (col/vals/scale) is wave-uniform:
// r is forced into an SGPR via readfirstlane so the compiler issues s_load
// for metadata and SALU for the gather base; the only vector work per edge
// is 1 global_load_dword (saddr + invariant lane offset) + 4 cvt + 4 fma.
// acc_dim = sum_e w_e * q_e[dim] - 128 * sum_e w_e,  w_e = vals_e * s_in[col_e]
// mode 0/1: quantize h -> q_out/s_out
// mode 2:   out = 0.25 * (x + dq(q1) + dq(q2) + h)
__global__ __launch_bounds__(256) void spmm_q_kernel(
    const unsigned char* __restrict__ q_in,
    const float* __restrict__ s_in,
    const float* __restrict__ vals,
    const int*   __restrict__ col,
    const int*   __restrict__ row_ptr,
    unsigned char* __restrict__ q_out,
    float* __restrict__ s_out,
    const float* __restrict__ x,
    const unsigned char* __restrict__ q1p, const float* __restrict__ s1p,
    const unsigned char* __restrict__ q2p, const float* __restrict__ s2p,
    float* __restrict__ out,
    int n_nodes, int mode)
{
    const int wave = threadIdx.x >> 6, lane = threadIdx.x & 63;
    const int r0 = blockIdx.x * 4 + wave;
    if (r0 >= n_nodes) return;
    // wave-uniform row id -> SGPR; everything derived becomes scalar
    const int r = __builtin_amdgcn_readfirstlane(r0);

    const int start = row_ptr[r];
    const int end   = row_ptr[r + 1];

    // per-lane gather pointer: SGPR base (c*256) + invariant lane offset
    const unsigned char* __restrict__ qlane = q_in + (unsigned int)(lane * 4);

    float ax = 0.f, ay = 0.f, az = 0.f, aw = 0.f;
    float wsum = 0.f;   // wave-uniform (every lane sums the same scalars)

    int e = start;
    for (; e + 4 <= end; e += 4) {
        const int c0 = col[e + 0], c1 = col[e + 1];
        const int c2 = col[e + 2], c3 = col[e + 3];
        const float w0 = vals[e + 0] * s_in[c0];
        const float w1 = vals[e + 1] * s_in[c1];
        const float w2 = vals[e + 2] * s_in[c2];
        const float w3 = vals[e + 3] * s_in[c3];
        const unsigned int g0 = *(const unsigned int*)(qlane + (size_t)c0 * 256);
        const unsigned int g1 = *(const unsigned int*)(qlane + (size_t)c1 * 256);
        const unsigned int g2 = *(const unsigned int*)(qlane + (size_t)c2 * 256);
        const unsigned int g3 = *(const unsigned int*)(qlane + (size_t)c3 * 256);
        wsum += (w0 + w1) + (w2 + w3);
        ax += w0 * (float)(g0 & 0xff);         ay += w0 * (float)((g0 >> 8) & 0xff);
        az += w0 * (float)((g0 >> 16) & 0xff); aw += w0 * (float)(g0 >> 24);
        ax += w1 * (float)(g1 & 0xff);         ay += w1 * (float)((g1 >> 8) & 0xff);
        az += w1 * (float)((g1 >> 16) & 0xff); aw += w1 * (float)(g1 >> 24);
        ax += w2 * (float)(g2 & 0xff);         ay += w2 * (float)((g2 >> 8) & 0xff);
        az += w2 * (float)((g2 >> 16) & 0xff); aw += w2 * (float)(g2 >> 24);
        ax += w3 * (float)(g3 & 0xff);         ay += w3 * (float)((g3 >> 8) & 0xff);
        az += w3 * (float)((g3 >> 16) & 0xff); aw += w3 * (float)(g3 >> 24);
    }
    for (; e < end; ++e) {
        const int   c = col[e];
        const float w = vals[e] * s_in[c];
        wsum += w;
        const unsigned int g = *(const unsigned int*)(qlane + (size_t)c * 256);
        ax += w * (float)(g & 0xff);         ay += w * (float)((g >> 8) & 0xff);
        az += w * (float)((g >> 16) & 0xff); aw += w * (float)(g >> 24);
    }

    // bias term: wsum is wave-uniform -> no reduction needed
    const float bias = 128.0f * wsum;
    const float px = ax - bias, py = ay - bias, pz = az - bias, pw = aw - bias;

    // wave-wide sum of squares for the row norm
    float s = px * px + py * py + pz * pz + pw * pw;
    #pragma unroll
    for (int off = 32; off; off >>= 1) s += __shfl_xor(s, off);

    const float sc = 1.0f / fmaxf(sqrtf(s), EPS);
    const float hx = px * sc, hy = py * sc, hz = pz * sc, hw = pw * sc;

    const long idx = (long)r * 64 + lane;

    if (mode < 2) {
        // quantize normalized h for the next layer's gather
        float m = fmaxf(fmaxf(fabsf(hx), fabsf(hy)), fmaxf(fabsf(hz), fabsf(hw)));
        #pragma unroll
        for (int off = 32; off; off >>= 1) m = fmaxf(m, __shfl_xor(m, off));
        const float mg  = fmaxf(m, 1e-30f);
        const float inv = 127.0f / mg;
        const unsigned int u0 = (unsigned int)(int)rintf(fmaf(hx, inv, 128.0f));
        const unsigned int u1 = (unsigned int)(int)rintf(fmaf(hy, inv, 128.0f));
        const unsigned int u2 = (unsigned int)(int)rintf(fmaf(hz, inv, 128.0f));
        const unsigned int u3 = (unsigned int)(int)rintf(fmaf(hw, inv, 128.0f));
        ((unsigned int*)q_out)[idx] = u0 | (u1 << 8) | (u2 << 16) | (u3 << 24);
        if (lane == 0) s_out[r] = mg * (1.0f / 127.0f);
    } else {
        // final combine: out = 0.25*(x + dq(q1) + dq(q2) + h)
        const float4 xv = ((const float4*)x)[idx];
        const unsigned int g1 = ((const unsigned int*)q1p)[idx];
        const unsigned int g2 = ((const unsigned int*)q2p)[idx];
        const float sc1 = s1p[r], sc2 = s2p[r];
        float4 o;
        o.x = 0.25f * (xv.x + ((float)(g1 & 0xff)         - 128.f) * sc1
                            + ((float)(g2 & 0xff)         - 128.f) * sc2 + hx);
        o.y = 0.25f * (xv.y + ((float)((g1 >> 8) & 0xff)  - 128.f) * sc1
                            + ((float)((g2 >> 8) & 0xff)  - 128.f) * sc2 + hy);
        o.z = 0.25f * (xv.z + ((float)((g1 >> 16) & 0xff) - 128.f) * sc1
                            + ((float)((g2 >> 16) & 0xff) - 128.f) * sc2 + hz);
        o.w = 0.25f * (xv.w + ((float)(g1 >> 24)          - 128.f) * sc1
                            + ((float)(g2 >> 24)          - 128.f) * sc2 + hw);
        ((float4*)out)[idx] = o;
    }
}

extern "C" void kernel_launch(void* const* d_in, const int* in_sizes, int n_in,
                              void* d_out, int out_size, void* d_ws, size_t ws_size,
                              hipStream_t stream) {
    const float* x    = (const float*)d_in[0];
    const float* vals = (const float*)d_in[1];
    const int*   row  = (const int*)d_in[2];
    const int*   col  = (const int*)d_in[3];
    float* out = (float*)d_out;

    const int N = in_sizes[0] / D_FEAT;   // 100000
    const int E = in_sizes[1];            // 1600000

    // workspace: row_ptr | xq | sx | q1 | s1 | q2 | s2   (all 1KB-aligned)
    auto align1k = [](size_t v) { return (v + 1023) & ~(size_t)1023; };
    const size_t rp_bytes = align1k((size_t)(N + 1) * sizeof(int));
    const size_t qbytes   = align1k((size_t)N * D_FEAT);           // uint8 rows
    const size_t sbytes   = align1k((size_t)N * sizeof(float));    // per-row scale
    char* ws = (char*)d_ws;
    int*           row_ptr = (int*)ws;                      ws += rp_bytes;
    unsigned char* xq = (unsigned char*)ws;                 ws += qbytes;
    float*         sx = (float*)ws;                         ws += sbytes;
    unsigned char* q1 = (unsigned char*)ws;                 ws += qbytes;
    float*         s1 = (float*)ws;                         ws += sbytes;
    unsigned char* q2 = (unsigned char*)ws;                 ws += qbytes;
    float*         s2 = (float*)ws;

    // 1. CSR offsets
    {
        const int threads = 256;
        const int blocks = (E + 1 + threads - 1) / threads;
        build_row_ptr_kernel<<<blocks, threads, 0, stream>>>(row, row_ptr, E, N);
    }

    const int blocks = (N + 3) / 4;  // one wave per row, 4 waves per block

    // 2. quantize x for the layer-0 gather
    quant_rows_kernel<<<blocks, 256, 0, stream>>>(x, xq, sx, N);

    // 3. three fused layers
    // L0: h1 = norm(A @ x)  -> q1/s1
    spmm_q_kernel<<<blocks, 256, 0, stream>>>(xq, sx, vals, col, row_ptr,
                                              q1, s1, x, q1, s1, q2, s2, out, N, 0);
    // L1: h2 = norm(A @ h1) -> q2/s2
    spmm_q_kernel<<<blocks, 256, 0, stream>>>(q1, s1, vals, col, row_ptr,
                                              q2, s2, x, q1, s1, q2, s2, out, N, 1);
    // L2: out = 0.25*(x + h1 + h2 + norm(A @ h2))
    spmm_q_kernel<<<blocks, 256, 0, stream>>>(q2, s2, vals, col, row_ptr,
                                              q2, s2, x, q1, s1, q2, s2, out, N, 2);
}

// Round 9
// 265.954 us; speedup vs baseline: 1.1104x; 1.1104x over previous
//
#include <hip/hip_runtime.h>
#include <hip/hip_bf16.h>

#define D_FEAT 256
#define EPS 1e-12f

// Build CSR row_ptr from sorted COO row array.
__global__ void build_row_ptr_kernel(const int* __restrict__ row,
                                     int* __restrict__ row_ptr,
                                     int E, int N) {
    int e = blockIdx.x * blockDim.x + threadIdx.x;
    if (e > E) return;
    int curr = (e == E) ? N : row[e];
    int prev = (e == 0) ? -1 : row[e - 1];
    for (int r = prev + 1; r <= curr; ++r) row_ptr[r] = e;
}

// Quantize fp32 rows -> biased uint8 (q = round(v/scale)+128) + per-row scale.
// One wave per row; lane l owns dims [4l, 4l+4).
__global__ __launch_bounds__(256) void quant_rows_kernel(
    const float* __restrict__ in,
    unsigned char* __restrict__ q,
    float* __restrict__ s,
    int n_rows)
{
    const int wave = threadIdx.x >> 6, lane = threadIdx.x & 63;
    const int r = blockIdx.x * 4 + wave;
    if (r >= n_rows) return;
    const long idx = (long)r * 64 + lane;
    const float4 f = ((const float4*)in)[idx];
    float m = fmaxf(fmaxf(fabsf(f.x), fabsf(f.y)), fmaxf(fabsf(f.z), fabsf(f.w)));
    #pragma unroll
    for (int off = 32; off; off >>= 1) m = fmaxf(m, __shfl_xor(m, off));
    const float mg  = fmaxf(m, 1e-30f);
    const float inv = 127.0f / mg;
    const unsigned int u0 = (unsigned int)(int)rintf(fmaf(f.x, inv, 128.0f));
    const unsigned int u1 = (unsigned int)(int)rintf(fmaf(f.y, inv, 128.0f));
    const unsigned int u2 = (unsigned int)(int)rintf(fmaf(f.z, inv, 128.0f));
    const unsigned int u3 = (unsigned int)(int)rintf(fmaf(f.w, inv, 128.0f));
    ((unsigned int*)q)[idx] = u0 | (u1 << 8) | (u2 << 16) | (u3 << 24);
    if (lane == 0) s[r] = mg * (1.0f / 127.0f);
}

// Fused SpMM (CSR, int8 features + per-row scale) + L2 normalize.
// One wave per output row; lane l owns dims [4l,4l+4) (one uint = 4B gather).
// Vector-lane metadata path (R6): 64 edges of (col, w) loaded lane-parallel,
// broadcast via __shfl; 4 gathers in flight per unrolled step.
// acc_dim = sum_e w_e * q_e[dim] - 128 * sum_e w_e,  w_e = vals_e * s_in[col_e]
// mode 0/1: quantize h -> q_out/s_out
// mode 2:   out = 0.25 * (dq(q0) + dq(q1) + dq(q2) + h)   [all-int8 combine]
__global__ __launch_bounds__(256) void spmm_q_kernel(
    const unsigned char* __restrict__ q_in,
    const float* __restrict__ s_in,
    const float* __restrict__ vals,
    const int*   __restrict__ col,
    const int*   __restrict__ row_ptr,
    unsigned char* __restrict__ q_out,
    float* __restrict__ s_out,
    const unsigned char* __restrict__ q0p, const float* __restrict__ s0p,
    const unsigned char* __restrict__ q1p, const float* __restrict__ s1p,
    const unsigned char* __restrict__ q2p, const float* __restrict__ s2p,
    float* __restrict__ out,
    int n_nodes, int mode)
{
    const int wave = threadIdx.x >> 6, lane = threadIdx.x & 63;
    const int r = blockIdx.x * 4 + wave;
    if (r >= n_nodes) return;

    const int start = row_ptr[r];
    const int end   = row_ptr[r + 1];

    const unsigned int* __restrict__ qi = (const unsigned int*)q_in;

    float ax = 0.f, ay = 0.f, az = 0.f, aw = 0.f;
    float wsum = 0.f;

    for (int base = start; base < end; base += 64) {
        const int n = min(64, end - base);
        float w = 0.f;
        int   c = 0;
        if (lane < n) {
            c = col[base + lane];
            w = vals[base + lane] * s_in[c];   // scale table: L2-resident 400KB
        }
        wsum += w;
        int j = 0;
        for (; j + 4 <= n; j += 4) {
            const int   c0 = __shfl(c, j + 0), c1 = __shfl(c, j + 1);
            const int   c2 = __shfl(c, j + 2), c3 = __shfl(c, j + 3);
            const float w0 = __shfl(w, j + 0), w1 = __shfl(w, j + 1);
            const float w2 = __shfl(w, j + 2), w3 = __shfl(w, j + 3);
            const unsigned int g0 = qi[(long)c0 * 64 + lane];
            const unsigned int g1 = qi[(long)c1 * 64 + lane];
            const unsigned int g2 = qi[(long)c2 * 64 + lane];
            const unsigned int g3 = qi[(long)c3 * 64 + lane];
            ax += w0 * (float)(g0 & 0xff);         ay += w0 * (float)((g0 >> 8) & 0xff);
            az += w0 * (float)((g0 >> 16) & 0xff); aw += w0 * (float)(g0 >> 24);
            ax += w1 * (float)(g1 & 0xff);         ay += w1 * (float)((g1 >> 8) & 0xff);
            az += w1 * (float)((g1 >> 16) & 0xff); aw += w1 * (float)(g1 >> 24);
            ax += w2 * (float)(g2 & 0xff);         ay += w2 * (float)((g2 >> 8) & 0xff);
            az += w2 * (float)((g2 >> 16) & 0xff); aw += w2 * (float)(g2 >> 24);
            ax += w3 * (float)(g3 & 0xff);         ay += w3 * (float)((g3 >> 8) & 0xff);
            az += w3 * (float)((g3 >> 16) & 0xff); aw += w3 * (float)(g3 >> 24);
        }
        for (; j < n; ++j) {
            const int   cj = __shfl(c, j);
            const float wj = __shfl(w, j);
            const unsigned int g = qi[(long)cj * 64 + lane];
            ax += wj * (float)(g & 0xff);         ay += wj * (float)((g >> 8) & 0xff);
            az += wj * (float)((g >> 16) & 0xff); aw += wj * (float)(g >> 24);
        }
    }

    // total edge weight (for the -128 bias term)
    float ws = wsum;
    #pragma unroll
    for (int off = 32; off; off >>= 1) ws += __shfl_xor(ws, off);
    const float bias = 128.0f * ws;

    const float px = ax - bias, py = ay - bias, pz = az - bias, pw = aw - bias;

    // wave-wide sum of squares for the row norm
    float s = px * px + py * py + pz * pz + pw * pw;
    #pragma unroll
    for (int off = 32; off; off >>= 1) s += __shfl_xor(s, off);

    const float sc = 1.0f / fmaxf(sqrtf(s), EPS);
    const float hx = px * sc, hy = py * sc, hz = pz * sc, hw = pw * sc;

    const long idx = (long)r * 64 + lane;

    if (mode < 2) {
        // quantize normalized h for the next layer's gather
        float m = fmaxf(fmaxf(fabsf(hx), fabsf(hy)), fmaxf(fabsf(hz), fabsf(hw)));
        #pragma unroll
        for (int off = 32; off; off >>= 1) m = fmaxf(m, __shfl_xor(m, off));
        const float mg  = fmaxf(m, 1e-30f);
        const float inv = 127.0f / mg;
        const unsigned int u0 = (unsigned int)(int)rintf(fmaf(hx, inv, 128.0f));
        const unsigned int u1 = (unsigned int)(int)rintf(fmaf(hy, inv, 128.0f));
        const unsigned int u2 = (unsigned int)(int)rintf(fmaf(hz, inv, 128.0f));
        const unsigned int u3 = (unsigned int)(int)rintf(fmaf(hw, inv, 128.0f));
        ((unsigned int*)q_out)[idx] = u0 | (u1 << 8) | (u2 << 16) | (u3 << 24);
        if (lane == 0) s_out[r] = mg * (1.0f / 127.0f);
    } else {
        // final combine: out = 0.25*(dq(q0) + dq(q1) + dq(q2) + h)
        // q0 = quantized x (saves streaming 102 MB of fp32 x; +<=0.0035 absmax)
        const unsigned int g0 = ((const unsigned int*)q0p)[idx];
        const unsigned int g1 = ((const unsigned int*)q1p)[idx];
        const unsigned int g2 = ((const unsigned int*)q2p)[idx];
        const float sc0 = s0p[r], sc1 = s1p[r], sc2 = s2p[r];
        float4 o;
        o.x = 0.25f * (((float)(g0 & 0xff)         - 128.f) * sc0
                     + ((float)(g1 & 0xff)         - 128.f) * sc1
                     + ((float)(g2 & 0xff)         - 128.f) * sc2 + hx);
        o.y = 0.25f * (((float)((g0 >> 8) & 0xff)  - 128.f) * sc0
                     + ((float)((g1 >> 8) & 0xff)  - 128.f) * sc1
                     + ((float)((g2 >> 8) & 0xff)  - 128.f) * sc2 + hy);
        o.z = 0.25f * (((float)((g0 >> 16) & 0xff) - 128.f) * sc0
                     + ((float)((g1 >> 16) & 0xff) - 128.f) * sc1
                     + ((float)((g2 >> 16) & 0xff) - 128.f) * sc2 + hz);
        o.w = 0.25f * (((float)(g0 >> 24)          - 128.f) * sc0
                     + ((float)(g1 >> 24)          - 128.f) * sc1
                     + ((float)(g2 >> 24)          - 128.f) * sc2 + hw);
        ((float4*)out)[idx] = o;
    }
}

extern "C" void kernel_launch(void* const* d_in, const int* in_sizes, int n_in,
                              void* d_out, int out_size, void* d_ws, size_t ws_size,
                              hipStream_t stream) {
    const float* x    = (const float*)d_in[0];
    const float* vals = (const float*)d_in[1];
    const int*   row  = (const int*)d_in[2];
    const int*   col  = (const int*)d_in[3];
    float* out = (float*)d_out;

    const int N = in_sizes[0] / D_FEAT;   // 100000
    const int E = in_sizes[1];            // 1600000

    // workspace: row_ptr | xq | sx | q1 | s1 | q2 | s2   (all 1KB-aligned)
    auto align1k = [](size_t v) { return (v + 1023) & ~(size_t)1023; };
    const size_t rp_bytes = align1k((size_t)(N + 1) * sizeof(int));
    const size_t qbytes   = align1k((size_t)N * D_FEAT);           // uint8 rows
    const size_t sbytes   = align1k((size_t)N * sizeof(float));    // per-row scale
    char* ws = (char*)d_ws;
    int*           row_ptr = (int*)ws;                      ws += rp_bytes;
    unsigned char* xq = (unsigned char*)ws;                 ws += qbytes;
    float*         sx = (float*)ws;                         ws += sbytes;
    unsigned char* q1 = (unsigned char*)ws;                 ws += qbytes;
    float*         s1 = (float*)ws;                         ws += sbytes;
    unsigned char* q2 = (unsigned char*)ws;                 ws += qbytes;
    float*         s2 = (float*)ws;

    // 1. CSR offsets
    {
        const int threads = 256;
        const int blocks = (E + 1 + threads - 1) / threads;
        build_row_ptr_kernel<<<blocks, threads, 0, stream>>>(row, row_ptr, E, N);
    }

    const int blocks = (N + 3) / 4;  // one wave per row, 4 waves per block

    // 2. quantize x for the layer-0 gather (and the final combine)
    quant_rows_kernel<<<blocks, 256, 0, stream>>>(x, xq, sx, N);

    // 3. three fused layers
    // L0: h1 = norm(A @ x)  -> q1/s1
    spmm_q_kernel<<<blocks, 256, 0, stream>>>(xq, sx, vals, col, row_ptr,
                                              q1, s1, xq, sx, q1, s1, q2, s2, out, N, 0);
    // L1: h2 = norm(A @ h1) -> q2/s2
    spmm_q_kernel<<<blocks, 256, 0, stream>>>(q1, s1, vals, col, row_ptr,
                                              q2, s2, xq, sx, q1, s1, q2, s2, out, N, 1);
    // L2: out = 0.25*(x + h1 + h2 + norm(A @ h2))   [x,h1,h2 from int8]
    spmm_q_kernel<<<blocks, 256, 0, stream>>>(q2, s2, vals, col, row_ptr,
                                              q2, s2, xq, sx, q1, s1, q2, s2, out, N, 2);
}

// Round 10
// 261.469 us; speedup vs baseline: 1.1294x; 1.0172x over previous
//
#include <hip/hip_runtime.h>
#include <hip/hip_bf16.h>

#define D_FEAT 256
#define EPS 1e-12f

// Build CSR row_ptr from sorted COO row array.
__global__ void build_row_ptr_kernel(const int* __restrict__ row,
                                     int* __restrict__ row_ptr,
                                     int E, int N) {
    int e = blockIdx.x * blockDim.x + threadIdx.x;
    if (e > E) return;
    int curr = (e == E) ? N : row[e];
    int prev = (e == 0) ? -1 : row[e - 1];
    for (int r = prev + 1; r <= curr; ++r) row_ptr[r] = e;
}

// Quantize fp32 rows -> biased uint8 (q = round(v/scale)+128) + per-row scale.
__global__ __launch_bounds__(256) void quant_rows_kernel(
    const float* __restrict__ in,
    unsigned char* __restrict__ q,
    float* __restrict__ s,
    int n_rows)
{
    const int wave = threadIdx.x >> 6, lane = threadIdx.x & 63;
    const int r = blockIdx.x * 4 + wave;
    if (r >= n_rows) return;
    const long idx = (long)r * 64 + lane;
    const float4 f = ((const float4*)in)[idx];
    float m = fmaxf(fmaxf(fabsf(f.x), fabsf(f.y)), fmaxf(fabsf(f.z), fabsf(f.w)));
    #pragma unroll
    for (int off = 32; off; off >>= 1) m = fmaxf(m, __shfl_xor(m, off));
    const float mg  = fmaxf(m, 1e-30f);
    const float inv = 127.0f / mg;
    const unsigned int u0 = (unsigned int)(int)rintf(fmaf(f.x, inv, 128.0f));
    const unsigned int u1 = (unsigned int)(int)rintf(fmaf(f.y, inv, 128.0f));
    const unsigned int u2 = (unsigned int)(int)rintf(fmaf(f.z, inv, 128.0f));
    const unsigned int u3 = (unsigned int)(int)rintf(fmaf(f.w, inv, 128.0f));
    ((unsigned int*)q)[idx] = u0 | (u1 << 8) | (u2 << 16) | (u3 << 24);
    if (lane == 0) s[r] = mg * (1.0f / 127.0f);
}

// Fused SpMM (CSR, int8 features + per-row scale) + L2 normalize + quantize.
// One wave per output row; lane l owns dims [4l,4l+4) (one uint = 4B gather).
// acc_dim = sum_e w_e * q_e[dim] - 128 * sum_e w_e,  w_e = vals_e * s_in[col_e]
// Writes int8 q_out/s_out always; when write_q4 != 0 also writes packed int4
// (nibbles, bias 8, per-row scale mg/7) for the next layer's cheap gather.
__global__ __launch_bounds__(256) void spmm_q_kernel(
    const unsigned char* __restrict__ q_in,
    const float* __restrict__ s_in,
    const float* __restrict__ vals,
    const int*   __restrict__ col,
    const int*   __restrict__ row_ptr,
    unsigned char* __restrict__ q_out,
    float* __restrict__ s_out,
    unsigned short* __restrict__ q4_out,
    float* __restrict__ s4_out,
    int n_nodes, int write_q4)
{
    const int wave = threadIdx.x >> 6, lane = threadIdx.x & 63;
    const int r = blockIdx.x * 4 + wave;
    if (r >= n_nodes) return;

    const int start = row_ptr[r];
    const int end   = row_ptr[r + 1];

    const unsigned int* __restrict__ qi = (const unsigned int*)q_in;

    float ax = 0.f, ay = 0.f, az = 0.f, aw = 0.f;
    float wsum = 0.f;

    for (int base = start; base < end; base += 64) {
        const int n = min(64, end - base);
        float w = 0.f;
        int   c = 0;
        if (lane < n) {
            c = col[base + lane];
            w = vals[base + lane] * s_in[c];
        }
        wsum += w;
        int j = 0;
        for (; j + 4 <= n; j += 4) {
            const int   c0 = __shfl(c, j + 0), c1 = __shfl(c, j + 1);
            const int   c2 = __shfl(c, j + 2), c3 = __shfl(c, j + 3);
            const float w0 = __shfl(w, j + 0), w1 = __shfl(w, j + 1);
            const float w2 = __shfl(w, j + 2), w3 = __shfl(w, j + 3);
            const unsigned int g0 = qi[(long)c0 * 64 + lane];
            const unsigned int g1 = qi[(long)c1 * 64 + lane];
            const unsigned int g2 = qi[(long)c2 * 64 + lane];
            const unsigned int g3 = qi[(long)c3 * 64 + lane];
            ax += w0 * (float)(g0 & 0xff);         ay += w0 * (float)((g0 >> 8) & 0xff);
            az += w0 * (float)((g0 >> 16) & 0xff); aw += w0 * (float)(g0 >> 24);
            ax += w1 * (float)(g1 & 0xff);         ay += w1 * (float)((g1 >> 8) & 0xff);
            az += w1 * (float)((g1 >> 16) & 0xff); aw += w1 * (float)(g1 >> 24);
            ax += w2 * (float)(g2 & 0xff);         ay += w2 * (float)((g2 >> 8) & 0xff);
            az += w2 * (float)((g2 >> 16) & 0xff); aw += w2 * (float)(g2 >> 24);
            ax += w3 * (float)(g3 & 0xff);         ay += w3 * (float)((g3 >> 8) & 0xff);
            az += w3 * (float)((g3 >> 16) & 0xff); aw += w3 * (float)(g3 >> 24);
        }
        for (; j < n; ++j) {
            const int   cj = __shfl(c, j);
            const float wj = __shfl(w, j);
            const unsigned int g = qi[(long)cj * 64 + lane];
            ax += wj * (float)(g & 0xff);         ay += wj * (float)((g >> 8) & 0xff);
            az += wj * (float)((g >> 16) & 0xff); aw += wj * (float)(g >> 24);
        }
    }

    float ws = wsum;
    #pragma unroll
    for (int off = 32; off; off >>= 1) ws += __shfl_xor(ws, off);
    const float bias = 128.0f * ws;

    const float px = ax - bias, py = ay - bias, pz = az - bias, pw = aw - bias;

    float s = px * px + py * py + pz * pz + pw * pw;
    #pragma unroll
    for (int off = 32; off; off >>= 1) s += __shfl_xor(s, off);

    const float sc = 1.0f / fmaxf(sqrtf(s), EPS);
    const float hx = px * sc, hy = py * sc, hz = pz * sc, hw = pw * sc;

    const long idx = (long)r * 64 + lane;

    // int8 quant (for combine read / next-layer int8 gather)
    float m = fmaxf(fmaxf(fabsf(hx), fabsf(hy)), fmaxf(fabsf(hz), fabsf(hw)));
    #pragma unroll
    for (int off = 32; off; off >>= 1) m = fmaxf(m, __shfl_xor(m, off));
    const float mg  = fmaxf(m, 1e-30f);
    const float inv = 127.0f / mg;
    const unsigned int u0 = (unsigned int)(int)rintf(fmaf(hx, inv, 128.0f));
    const unsigned int u1 = (unsigned int)(int)rintf(fmaf(hy, inv, 128.0f));
    const unsigned int u2 = (unsigned int)(int)rintf(fmaf(hz, inv, 128.0f));
    const unsigned int u3 = (unsigned int)(int)rintf(fmaf(hw, inv, 128.0f));
    ((unsigned int*)q_out)[idx] = u0 | (u1 << 8) | (u2 << 16) | (u3 << 24);
    if (lane == 0) s_out[r] = mg * (1.0f / 127.0f);

    if (write_q4) {
        // packed int4 copy for the next layer's 2B/lane gather
        const float inv4 = 7.0f / mg;
        const unsigned int n0 = ((unsigned int)((int)rintf(hx * inv4) + 8)) & 15u;
        const unsigned int n1 = ((unsigned int)((int)rintf(hy * inv4) + 8)) & 15u;
        const unsigned int n2 = ((unsigned int)((int)rintf(hz * inv4) + 8)) & 15u;
        const unsigned int n3 = ((unsigned int)((int)rintf(hw * inv4) + 8)) & 15u;
        q4_out[idx] = (unsigned short)(n0 | (n1 << 4) | (n2 << 8) | (n3 << 12));
        if (lane == 0) s4_out[r] = mg * (1.0f / 7.0f);
    }
}

// Final layer: SpMM gathering packed int4 (2B/lane) + normalize + combine.
// out = 0.25 * (dq(q0) + dq(q1) + dq(q2) + h3)
__global__ __launch_bounds__(256) void spmm_q4_combine_kernel(
    const unsigned short* __restrict__ q4_in,
    const float* __restrict__ s4_in,
    const float* __restrict__ vals,
    const int*   __restrict__ col,
    const int*   __restrict__ row_ptr,
    const unsigned char* __restrict__ q0p, const float* __restrict__ s0p,
    const unsigned char* __restrict__ q1p, const float* __restrict__ s1p,
    const unsigned char* __restrict__ q2p, const float* __restrict__ s2p,
    float* __restrict__ out,
    int n_nodes)
{
    const int wave = threadIdx.x >> 6, lane = threadIdx.x & 63;
    const int r = blockIdx.x * 4 + wave;
    if (r >= n_nodes) return;

    const int start = row_ptr[r];
    const int end   = row_ptr[r + 1];

    const unsigned short* __restrict__ qlane = q4_in + lane;  // row stride 64 ushorts

    float ax = 0.f, ay = 0.f, az = 0.f, aw = 0.f;
    float wsum = 0.f;

    for (int base = start; base < end; base += 64) {
        const int n = min(64, end - base);
        float w = 0.f;
        int   c = 0;
        if (lane < n) {
            c = col[base + lane];
            w = vals[base + lane] * s4_in[c];
        }
        wsum += w;
        int j = 0;
        for (; j + 4 <= n; j += 4) {
            const int   c0 = __shfl(c, j + 0), c1 = __shfl(c, j + 1);
            const int   c2 = __shfl(c, j + 2), c3 = __shfl(c, j + 3);
            const float w0 = __shfl(w, j + 0), w1 = __shfl(w, j + 1);
            const float w2 = __shfl(w, j + 2), w3 = __shfl(w, j + 3);
            const unsigned int g0 = qlane[(long)c0 * 64];
            const unsigned int g1 = qlane[(long)c1 * 64];
            const unsigned int g2 = qlane[(long)c2 * 64];
            const unsigned int g3 = qlane[(long)c3 * 64];
            ax += w0 * (float)(g0 & 0xF);        ay += w0 * (float)((g0 >> 4) & 0xF);
            az += w0 * (float)((g0 >> 8) & 0xF); aw += w0 * (float)(g0 >> 12);
            ax += w1 * (float)(g1 & 0xF);        ay += w1 * (float)((g1 >> 4) & 0xF);
            az += w1 * (float)((g1 >> 8) & 0xF); aw += w1 * (float)(g1 >> 12);
            ax += w2 * (float)(g2 & 0xF);        ay += w2 * (float)((g2 >> 4) & 0xF);
            az += w2 * (float)((g2 >> 8) & 0xF); aw += w2 * (float)(g2 >> 12);
            ax += w3 * (float)(g3 & 0xF);        ay += w3 * (float)((g3 >> 4) & 0xF);
            az += w3 * (float)((g3 >> 8) & 0xF); aw += w3 * (float)(g3 >> 12);
        }
        for (; j < n; ++j) {
            const int   cj = __shfl(c, j);
            const float wj = __shfl(w, j);
            const unsigned int g = qlane[(long)cj * 64];
            ax += wj * (float)(g & 0xF);        ay += wj * (float)((g >> 4) & 0xF);
            az += wj * (float)((g >> 8) & 0xF); aw += wj * (float)(g >> 12);
        }
    }

    float wsr = wsum;
    #pragma unroll
    for (int off = 32; off; off >>= 1) wsr += __shfl_xor(wsr, off);
    const float bias = 8.0f * wsr;   // int4 bias center is 8

    const float px = ax - bias, py = ay - bias, pz = az - bias, pw = aw - bias;

    float s = px * px + py * py + pz * pz + pw * pw;
    #pragma unroll
    for (int off = 32; off; off >>= 1) s += __shfl_xor(s, off);

    const float sc = 1.0f / fmaxf(sqrtf(s), EPS);
    const float hx = px * sc, hy = py * sc, hz = pz * sc, hw = pw * sc;

    const long idx = (long)r * 64 + lane;

    const unsigned int g0 = ((const unsigned int*)q0p)[idx];
    const unsigned int g1 = ((const unsigned int*)q1p)[idx];
    const unsigned int g2 = ((const unsigned int*)q2p)[idx];
    const float sc0 = s0p[r], sc1 = s1p[r], sc2 = s2p[r];
    float4 o;
    o.x = 0.25f * (((float)(g0 & 0xff)         - 128.f) * sc0
                 + ((float)(g1 & 0xff)         - 128.f) * sc1
                 + ((float)(g2 & 0xff)         - 128.f) * sc2 + hx);
    o.y = 0.25f * (((float)((g0 >> 8) & 0xff)  - 128.f) * sc0
                 + ((float)((g1 >> 8) & 0xff)  - 128.f) * sc1
                 + ((float)((g2 >> 8) & 0xff)  - 128.f) * sc2 + hy);
    o.z = 0.25f * (((float)((g0 >> 16) & 0xff) - 128.f) * sc0
                 + ((float)((g1 >> 16) & 0xff) - 128.f) * sc1
                 + ((float)((g2 >> 16) & 0xff) - 128.f) * sc2 + hz);
    o.w = 0.25f * (((float)(g0 >> 24)          - 128.f) * sc0
                 + ((float)(g1 >> 24)          - 128.f) * sc1
                 + ((float)(g2 >> 24)          - 128.f) * sc2 + hw);
    ((float4*)out)[idx] = o;
}

extern "C" void kernel_launch(void* const* d_in, const int* in_sizes, int n_in,
                              void* d_out, int out_size, void* d_ws, size_t ws_size,
                              hipStream_t stream) {
    const float* x    = (const float*)d_in[0];
    const float* vals = (const float*)d_in[1];
    const int*   row  = (const int*)d_in[2];
    const int*   col  = (const int*)d_in[3];
    float* out = (float*)d_out;

    const int N = in_sizes[0] / D_FEAT;   // 100000
    const int E = in_sizes[1];            // 1600000

    // workspace: row_ptr | xq | sx | q1 | s1 | q2 | s2 | q2n | s2n
    auto align1k = [](size_t v) { return (v + 1023) & ~(size_t)1023; };
    const size_t rp_bytes = align1k((size_t)(N + 1) * sizeof(int));
    const size_t qbytes   = align1k((size_t)N * D_FEAT);               // int8 rows
    const size_t q4bytes  = align1k((size_t)N * D_FEAT / 2);           // int4 rows
    const size_t sbytes   = align1k((size_t)N * sizeof(float));
    char* ws = (char*)d_ws;
    int*            row_ptr = (int*)ws;            ws += rp_bytes;
    unsigned char*  xq  = (unsigned char*)ws;      ws += qbytes;
    float*          sx  = (float*)ws;              ws += sbytes;
    unsigned char*  q1  = (unsigned char*)ws;      ws += qbytes;
    float*          s1  = (float*)ws;              ws += sbytes;
    unsigned char*  q2  = (unsigned char*)ws;      ws += qbytes;
    float*          s2  = (float*)ws;              ws += sbytes;
    unsigned short* q2n = (unsigned short*)ws;     ws += q4bytes;
    float*          s2n = (float*)ws;

    // 1. CSR offsets
    {
        const int threads = 256;
        const int blocks = (E + 1 + threads - 1) / threads;
        build_row_ptr_kernel<<<blocks, threads, 0, stream>>>(row, row_ptr, E, N);
    }

    const int blocks = (N + 3) / 4;  // one wave per row, 4 waves per block

    // 2. quantize x (layer-0 gather table + combine term)
    quant_rows_kernel<<<blocks, 256, 0, stream>>>(x, xq, sx, N);

    // 3. three fused layers
    // L0: h1 = norm(A @ x)  -> q1/s1 (int8)
    spmm_q_kernel<<<blocks, 256, 0, stream>>>(xq, sx, vals, col, row_ptr,
                                              q1, s1, q2n, s2n, N, 0);
    // L1: h2 = norm(A @ h1) -> q2/s2 (int8) + q2n/s2n (int4, for L2 gather)
    spmm_q_kernel<<<blocks, 256, 0, stream>>>(q1, s1, vals, col, row_ptr,
                                              q2, s2, q2n, s2n, N, 1);
    // L2: out = 0.25*(x + h1 + h2 + norm(A @ h2))  [gather int4, combine int8]
    spmm_q4_combine_kernel<<<blocks, 256, 0, stream>>>(q2n, s2n, vals, col, row_ptr,
                                                       xq, sx, q1, s1, q2, s2, out, N);
}

// Round 11
// 259.311 us; speedup vs baseline: 1.1388x; 1.0083x over previous
//
#include <hip/hip_runtime.h>
#include <hip/hip_bf16.h>

#define D_FEAT 256
#define EPS 1e-12f

// Build CSR row_ptr from sorted COO row array.
__global__ void build_row_ptr_kernel(const int* __restrict__ row,
                                     int* __restrict__ row_ptr,
                                     int E, int N) {
    int e = blockIdx.x * blockDim.x + threadIdx.x;
    if (e > E) return;
    int curr = (e == E) ? N : row[e];
    int prev = (e == 0) ? -1 : row[e - 1];
    for (int r = prev + 1; r <= curr; ++r) row_ptr[r] = e;
}

// Quantize fp32 rows -> biased uint8 (q = round(v/scale)+128) + per-row scale.
__global__ __launch_bounds__(256) void quant_rows_kernel(
    const float* __restrict__ in,
    unsigned char* __restrict__ q,
    float* __restrict__ s,
    int n_rows)
{
    const int wave = threadIdx.x >> 6, lane = threadIdx.x & 63;
    const int r = blockIdx.x * 4 + wave;
    if (r >= n_rows) return;
    const long idx = (long)r * 64 + lane;
    const float4 f = ((const float4*)in)[idx];
    float m = fmaxf(fmaxf(fabsf(f.x), fabsf(f.y)), fmaxf(fabsf(f.z), fabsf(f.w)));
    #pragma unroll
    for (int off = 32; off; off >>= 1) m = fmaxf(m, __shfl_xor(m, off));
    const float mg  = fmaxf(m, 1e-30f);
    const float inv = 127.0f / mg;
    const unsigned int u0 = (unsigned int)(int)rintf(fmaf(f.x, inv, 128.0f));
    const unsigned int u1 = (unsigned int)(int)rintf(fmaf(f.y, inv, 128.0f));
    const unsigned int u2 = (unsigned int)(int)rintf(fmaf(f.z, inv, 128.0f));
    const unsigned int u3 = (unsigned int)(int)rintf(fmaf(f.w, inv, 128.0f));
    ((unsigned int*)q)[idx] = u0 | (u1 << 8) | (u2 << 16) | (u3 << 24);
    if (lane == 0) s[r] = mg * (1.0f / 127.0f);
}

// L0: SpMM over int8 table + L2 normalize; writes int8 AND packed-int4 h.
__global__ __launch_bounds__(256) void spmm_q_kernel(
    const unsigned char* __restrict__ q_in,
    const float* __restrict__ s_in,
    const float* __restrict__ vals,
    const int*   __restrict__ col,
    const int*   __restrict__ row_ptr,
    unsigned char* __restrict__ q_out,
    float* __restrict__ s_out,
    unsigned short* __restrict__ q4_out,
    float* __restrict__ s4_out,
    int n_nodes)
{
    const int wave = threadIdx.x >> 6, lane = threadIdx.x & 63;
    const int r = blockIdx.x * 4 + wave;
    if (r >= n_nodes) return;

    const int start = row_ptr[r];
    const int end   = row_ptr[r + 1];

    const unsigned int* __restrict__ qi = (const unsigned int*)q_in;

    float ax = 0.f, ay = 0.f, az = 0.f, aw = 0.f;
    float wsum = 0.f;

    for (int base = start; base < end; base += 64) {
        const int n = min(64, end - base);
        float w = 0.f;
        int   c = 0;
        if (lane < n) {
            c = col[base + lane];
            w = vals[base + lane] * s_in[c];
        }
        wsum += w;
        int j = 0;
        for (; j + 4 <= n; j += 4) {
            const int   c0 = __shfl(c, j + 0), c1 = __shfl(c, j + 1);
            const int   c2 = __shfl(c, j + 2), c3 = __shfl(c, j + 3);
            const float w0 = __shfl(w, j + 0), w1 = __shfl(w, j + 1);
            const float w2 = __shfl(w, j + 2), w3 = __shfl(w, j + 3);
            const unsigned int g0 = qi[(long)c0 * 64 + lane];
            const unsigned int g1 = qi[(long)c1 * 64 + lane];
            const unsigned int g2 = qi[(long)c2 * 64 + lane];
            const unsigned int g3 = qi[(long)c3 * 64 + lane];
            ax += w0 * (float)(g0 & 0xff);         ay += w0 * (float)((g0 >> 8) & 0xff);
            az += w0 * (float)((g0 >> 16) & 0xff); aw += w0 * (float)(g0 >> 24);
            ax += w1 * (float)(g1 & 0xff);         ay += w1 * (float)((g1 >> 8) & 0xff);
            az += w1 * (float)((g1 >> 16) & 0xff); aw += w1 * (float)(g1 >> 24);
            ax += w2 * (float)(g2 & 0xff);         ay += w2 * (float)((g2 >> 8) & 0xff);
            az += w2 * (float)((g2 >> 16) & 0xff); aw += w2 * (float)(g2 >> 24);
            ax += w3 * (float)(g3 & 0xff);         ay += w3 * (float)((g3 >> 8) & 0xff);
            az += w3 * (float)((g3 >> 16) & 0xff); aw += w3 * (float)(g3 >> 24);
        }
        for (; j < n; ++j) {
            const int   cj = __shfl(c, j);
            const float wj = __shfl(w, j);
            const unsigned int g = qi[(long)cj * 64 + lane];
            ax += wj * (float)(g & 0xff);         ay += wj * (float)((g >> 8) & 0xff);
            az += wj * (float)((g >> 16) & 0xff); aw += wj * (float)(g >> 24);
        }
    }

    float ws = wsum;
    #pragma unroll
    for (int off = 32; off; off >>= 1) ws += __shfl_xor(ws, off);
    const float bias = 128.0f * ws;

    const float px = ax - bias, py = ay - bias, pz = az - bias, pw = aw - bias;

    float s = px * px + py * py + pz * pz + pw * pw;
    #pragma unroll
    for (int off = 32; off; off >>= 1) s += __shfl_xor(s, off);

    const float sc = 1.0f / fmaxf(sqrtf(s), EPS);
    const float hx = px * sc, hy = py * sc, hz = pz * sc, hw = pw * sc;

    const long idx = (long)r * 64 + lane;

    float m = fmaxf(fmaxf(fabsf(hx), fabsf(hy)), fmaxf(fabsf(hz), fabsf(hw)));
    #pragma unroll
    for (int off = 32; off; off >>= 1) m = fmaxf(m, __shfl_xor(m, off));
    const float mg  = fmaxf(m, 1e-30f);
    const float inv = 127.0f / mg;
    const unsigned int u0 = (unsigned int)(int)rintf(fmaf(hx, inv, 128.0f));
    const unsigned int u1 = (unsigned int)(int)rintf(fmaf(hy, inv, 128.0f));
    const unsigned int u2 = (unsigned int)(int)rintf(fmaf(hz, inv, 128.0f));
    const unsigned int u3 = (unsigned int)(int)rintf(fmaf(hw, inv, 128.0f));
    ((unsigned int*)q_out)[idx] = u0 | (u1 << 8) | (u2 << 16) | (u3 << 24);
    if (lane == 0) s_out[r] = mg * (1.0f / 127.0f);

    const float inv4 = 7.0f / mg;
    const unsigned int n0 = ((unsigned int)((int)rintf(hx * inv4) + 8)) & 15u;
    const unsigned int n1 = ((unsigned int)((int)rintf(hy * inv4) + 8)) & 15u;
    const unsigned int n2 = ((unsigned int)((int)rintf(hz * inv4) + 8)) & 15u;
    const unsigned int n3 = ((unsigned int)((int)rintf(hw * inv4) + 8)) & 15u;
    q4_out[idx] = (unsigned short)(n0 | (n1 << 4) | (n2 << 8) | (n3 << 12));
    if (lane == 0) s4_out[r] = mg * (1.0f / 7.0f);
}

// L1/L2: SpMM over packed-int4 table (2B/lane) with cheap byte-cvt decode:
//   SA=sum w*(n0+16n1), SB=sum w*(n1+16n2), SC=sum w*(n2+16n3), SD=sum w*n3
//   then A3=SD, A2=SC-16A3, A1=SB-16A2, A0=SA-16A1 (exact separation).
// mode 0/1: + normalize + write int8 and int4 h tables
// mode 2:   + normalize + combine: out = 0.25*(dq(q0)+dq(q1)+dq(q2)+h)
__global__ __launch_bounds__(256) void spmm_q4_kernel(
    const unsigned short* __restrict__ q4_in,
    const float* __restrict__ s4_in,
    const float* __restrict__ vals,
    const int*   __restrict__ col,
    const int*   __restrict__ row_ptr,
    unsigned char* __restrict__ q_out,
    float* __restrict__ s_out,
    unsigned short* __restrict__ q4_out,
    float* __restrict__ s4_out,
    const unsigned char* __restrict__ q0p, const float* __restrict__ s0p,
    const unsigned char* __restrict__ q1p, const float* __restrict__ s1p,
    const unsigned char* __restrict__ q2p, const float* __restrict__ s2p,
    float* __restrict__ out,
    int n_nodes, int mode)
{
    const int wave = threadIdx.x >> 6, lane = threadIdx.x & 63;
    const int r = blockIdx.x * 4 + wave;
    if (r >= n_nodes) return;

    const int start = row_ptr[r];
    const int end   = row_ptr[r + 1];

    const unsigned short* __restrict__ qlane = q4_in + lane;  // row stride 64 ushorts

    float sa = 0.f, sb = 0.f, sc4 = 0.f, sd = 0.f;
    float wsum = 0.f;

    for (int base = start; base < end; base += 64) {
        const int n = min(64, end - base);
        float w = 0.f;
        int   c = 0;
        if (lane < n) {
            c = col[base + lane];
            w = vals[base + lane] * s4_in[c];
        }
        wsum += w;
        int j = 0;
        for (; j + 4 <= n; j += 4) {
            const int   c0 = __shfl(c, j + 0), c1 = __shfl(c, j + 1);
            const int   c2 = __shfl(c, j + 2), c3 = __shfl(c, j + 3);
            const float w0 = __shfl(w, j + 0), w1 = __shfl(w, j + 1);
            const float w2 = __shfl(w, j + 2), w3 = __shfl(w, j + 3);
            const unsigned int g0 = qlane[(long)c0 * 64];
            const unsigned int g1 = qlane[(long)c1 * 64];
            const unsigned int g2 = qlane[(long)c2 * 64];
            const unsigned int g3 = qlane[(long)c3 * 64];
            sa  += w0 * (float)(g0 & 0xffu);
            sb  += w0 * (float)((g0 >> 4) & 0xffu);
            sc4 += w0 * (float)((g0 >> 8) & 0xffu);
            sd  += w0 * (float)(g0 >> 12);
            sa  += w1 * (float)(g1 & 0xffu);
            sb  += w1 * (float)((g1 >> 4) & 0xffu);
            sc4 += w1 * (float)((g1 >> 8) & 0xffu);
            sd  += w1 * (float)(g1 >> 12);
            sa  += w2 * (float)(g2 & 0xffu);
            sb  += w2 * (float)((g2 >> 4) & 0xffu);
            sc4 += w2 * (float)((g2 >> 8) & 0xffu);
            sd  += w2 * (float)(g2 >> 12);
            sa  += w3 * (float)(g3 & 0xffu);
            sb  += w3 * (float)((g3 >> 4) & 0xffu);
            sc4 += w3 * (float)((g3 >> 8) & 0xffu);
            sd  += w3 * (float)(g3 >> 12);
        }
        for (; j < n; ++j) {
            const int   cj = __shfl(c, j);
            const float wj = __shfl(w, j);
            const unsigned int g = qlane[(long)cj * 64];
            sa  += wj * (float)(g & 0xffu);
            sb  += wj * (float)((g >> 4) & 0xffu);
            sc4 += wj * (float)((g >> 8) & 0xffu);
            sd  += wj * (float)(g >> 12);
        }
    }

    // separate the mixed accumulators (exact)
    const float a3 = sd;
    const float a2 = sc4 - 16.0f * a3;
    const float a1 = sb  - 16.0f * a2;
    const float a0 = sa  - 16.0f * a1;

    float ws = wsum;
    #pragma unroll
    for (int off = 32; off; off >>= 1) ws += __shfl_xor(ws, off);
    const float bias = 8.0f * ws;   // int4 bias center

    const float px = a0 - bias, py = a1 - bias, pz = a2 - bias, pw = a3 - bias;

    float s = px * px + py * py + pz * pz + pw * pw;
    #pragma unroll
    for (int off = 32; off; off >>= 1) s += __shfl_xor(s, off);

    const float sc = 1.0f / fmaxf(sqrtf(s), EPS);
    const float hx = px * sc, hy = py * sc, hz = pz * sc, hw = pw * sc;

    const long idx = (long)r * 64 + lane;

    if (mode < 2) {
        float m = fmaxf(fmaxf(fabsf(hx), fabsf(hy)), fmaxf(fabsf(hz), fabsf(hw)));
        #pragma unroll
        for (int off = 32; off; off >>= 1) m = fmaxf(m, __shfl_xor(m, off));
        const float mg  = fmaxf(m, 1e-30f);
        const float inv = 127.0f / mg;
        const unsigned int u0 = (unsigned int)(int)rintf(fmaf(hx, inv, 128.0f));
        const unsigned int u1 = (unsigned int)(int)rintf(fmaf(hy, inv, 128.0f));
        const unsigned int u2 = (unsigned int)(int)rintf(fmaf(hz, inv, 128.0f));
        const unsigned int u3 = (unsigned int)(int)rintf(fmaf(hw, inv, 128.0f));
        ((unsigned int*)q_out)[idx] = u0 | (u1 << 8) | (u2 << 16) | (u3 << 24);
        if (lane == 0) s_out[r] = mg * (1.0f / 127.0f);

        const float inv4 = 7.0f / mg;
        const unsigned int n0 = ((unsigned int)((int)rintf(hx * inv4) + 8)) & 15u;
        const unsigned int n1 = ((unsigned int)((int)rintf(hy * inv4) + 8)) & 15u;
        const unsigned int n2 = ((unsigned int)((int)rintf(hz * inv4) + 8)) & 15u;
        const unsigned int n3 = ((unsigned int)((int)rintf(hw * inv4) + 8)) & 15u;
        q4_out[idx] = (unsigned short)(n0 | (n1 << 4) | (n2 << 8) | (n3 << 12));
        if (lane == 0) s4_out[r] = mg * (1.0f / 7.0f);
    } else {
        const unsigned int g0 = ((const unsigned int*)q0p)[idx];
        const unsigned int g1 = ((const unsigned int*)q1p)[idx];
        const unsigned int g2 = ((const unsigned int*)q2p)[idx];
        const float sc0 = s0p[r], sc1 = s1p[r], sc2 = s2p[r];
        float4 o;
        o.x = 0.25f * (((float)(g0 & 0xff)         - 128.f) * sc0
                     + ((float)(g1 & 0xff)         - 128.f) * sc1
                     + ((float)(g2 & 0xff)         - 128.f) * sc2 + hx);
        o.y = 0.25f * (((float)((g0 >> 8) & 0xff)  - 128.f) * sc0
                     + ((float)((g1 >> 8) & 0xff)  - 128.f) * sc1
                     + ((float)((g2 >> 8) & 0xff)  - 128.f) * sc2 + hy);
        o.z = 0.25f * (((float)((g0 >> 16) & 0xff) - 128.f) * sc0
                     + ((float)((g1 >> 16) & 0xff) - 128.f) * sc1
                     + ((float)((g2 >> 16) & 0xff) - 128.f) * sc2 + hz);
        o.w = 0.25f * (((float)(g0 >> 24)          - 128.f) * sc0
                     + ((float)(g1 >> 24)          - 128.f) * sc1
                     + ((float)(g2 >> 24)          - 128.f) * sc2 + hw);
        ((float4*)out)[idx] = o;
    }
}

extern "C" void kernel_launch(void* const* d_in, const int* in_sizes, int n_in,
                              void* d_out, int out_size, void* d_ws, size_t ws_size,
                              hipStream_t stream) {
    const float* x    = (const float*)d_in[0];
    const float* vals = (const float*)d_in[1];
    const int*   row  = (const int*)d_in[2];
    const int*   col  = (const int*)d_in[3];
    float* out = (float*)d_out;

    const int N = in_sizes[0] / D_FEAT;   // 100000
    const int E = in_sizes[1];            // 1600000

    // workspace: row_ptr | xq | sx | q1 | s1 | q2 | s2 | q1n | s1n | q2n | s2n
    auto align1k = [](size_t v) { return (v + 1023) & ~(size_t)1023; };
    const size_t rp_bytes = align1k((size_t)(N + 1) * sizeof(int));
    const size_t qbytes   = align1k((size_t)N * D_FEAT);               // int8 rows
    const size_t q4bytes  = align1k((size_t)N * D_FEAT / 2);           // int4 rows
    const size_t sbytes   = align1k((size_t)N * sizeof(float));
    char* ws = (char*)d_ws;
    int*            row_ptr = (int*)ws;            ws += rp_bytes;
    unsigned char*  xq  = (unsigned char*)ws;      ws += qbytes;
    float*          sx  = (float*)ws;              ws += sbytes;
    unsigned char*  q1  = (unsigned char*)ws;      ws += qbytes;
    float*          s1  = (float*)ws;              ws += sbytes;
    unsigned char*  q2  = (unsigned char*)ws;      ws += qbytes;
    float*          s2  = (float*)ws;              ws += sbytes;
    unsigned short* q1n = (unsigned short*)ws;     ws += q4bytes;
    float*          s1n = (float*)ws;              ws += sbytes;
    unsigned short* q2n = (unsigned short*)ws;     ws += q4bytes;
    float*          s2n = (float*)ws;

    // 1. CSR offsets
    {
        const int threads = 256;
        const int blocks = (E + 1 + threads - 1) / threads;
        build_row_ptr_kernel<<<blocks, threads, 0, stream>>>(row, row_ptr, E, N);
    }

    const int blocks = (N + 3) / 4;  // one wave per row, 4 waves per block

    // 2. quantize x (layer-0 int8 gather table + combine term)
    quant_rows_kernel<<<blocks, 256, 0, stream>>>(x, xq, sx, N);

    // 3. three fused layers
    // L0 (int8 gather): h1 -> q1/s1 (int8) + q1n/s1n (int4)
    spmm_q_kernel<<<blocks, 256, 0, stream>>>(xq, sx, vals, col, row_ptr,
                                              q1, s1, q1n, s1n, N);
    // L1 (int4 gather): h2 -> q2/s2 (int8) + q2n/s2n (int4)
    spmm_q4_kernel<<<blocks, 256, 0, stream>>>(q1n, s1n, vals, col, row_ptr,
                                               q2, s2, q2n, s2n,
                                               xq, sx, q1, s1, q2, s2, out, N, 0);
    // L2 (int4 gather + combine): out = 0.25*(x + h1 + h2 + h3)
    spmm_q4_kernel<<<blocks, 256, 0, stream>>>(q2n, s2n, vals, col, row_ptr,
                                               q2, s2, q2n, s2n,
                                               xq, sx, q1, s1, q2, s2, out, N, 2);
}

// Round 12
// 245.524 us; speedup vs baseline: 1.2028x; 1.0562x over previous
//
#include <hip/hip_runtime.h>
#include <hip/hip_bf16.h>

#define D_FEAT 256
#define EPS 1e-12f

// Build CSR row_ptr from sorted COO row array.
__global__ void build_row_ptr_kernel(const int* __restrict__ row,
                                     int* __restrict__ row_ptr,
                                     int E, int N) {
    int e = blockIdx.x * blockDim.x + threadIdx.x;
    if (e > E) return;
    int curr = (e == E) ? N : row[e];
    int prev = (e == 0) ? -1 : row[e - 1];
    for (int r = prev + 1; r <= curr; ++r) row_ptr[r] = e;
}

// Quantize fp32 rows -> biased uint8 (q = round(v/scale)+128) + per-row scale.
__global__ __launch_bounds__(256) void quant_rows_kernel(
    const float* __restrict__ in,
    unsigned char* __restrict__ q,
    float* __restrict__ s,
    int n_rows)
{
    const int wave = threadIdx.x >> 6, lane = threadIdx.x & 63;
    const int r = blockIdx.x * 4 + wave;
    if (r >= n_rows) return;
    const long idx = (long)r * 64 + lane;
    const float4 f = ((const float4*)in)[idx];
    float m = fmaxf(fmaxf(fabsf(f.x), fabsf(f.y)), fmaxf(fabsf(f.z), fabsf(f.w)));
    #pragma unroll
    for (int off = 32; off; off >>= 1) m = fmaxf(m, __shfl_xor(m, off));
    const float mg  = fmaxf(m, 1e-30f);
    const float inv = 127.0f / mg;
    const unsigned int u0 = (unsigned int)(int)rintf(fmaf(f.x, inv, 128.0f));
    const unsigned int u1 = (unsigned int)(int)rintf(fmaf(f.y, inv, 128.0f));
    const unsigned int u2 = (unsigned int)(int)rintf(fmaf(f.z, inv, 128.0f));
    const unsigned int u3 = (unsigned int)(int)rintf(fmaf(f.w, inv, 128.0f));
    ((unsigned int*)q)[idx] = u0 | (u1 << 8) | (u2 << 16) | (u3 << 24);
    if (lane == 0) s[r] = mg * (1.0f / 127.0f);
}

// L0: SpMM over int8 table + L2 normalize; writes int8 AND packed-int4 h.
// One wave per row. Edge metadata staged in LDS once, read back with a
// wave-uniform address (LDS broadcast, no bpermute). Gather uses 32-bit
// voffset + uniform SGPR base (saddr form): 1 v_add per gather.
__global__ __launch_bounds__(256) void spmm_q_kernel(
    const unsigned char* __restrict__ q_in,
    const float* __restrict__ s_in,
    const float* __restrict__ vals,
    const int*   __restrict__ col,
    const int*   __restrict__ row_ptr,
    unsigned char* __restrict__ q_out,
    float* __restrict__ s_out,
    unsigned short* __restrict__ q4_out,
    float* __restrict__ s4_out,
    int n_nodes)
{
    __shared__ float    ldsw[4][64];
    __shared__ unsigned ldso[4][64];

    const int wave = threadIdx.x >> 6, lane = threadIdx.x & 63;
    const int r = blockIdx.x * 4 + wave;
    if (r >= n_nodes) return;

    const int start = row_ptr[r];
    const int end   = row_ptr[r + 1];
    const unsigned lane4 = (unsigned)lane * 4u;

    float ax = 0.f, ay = 0.f, az = 0.f, aw = 0.f;
    float wsum = 0.f;   // wave-uniform (broadcast adds)

    for (int base = start; base < end; base += 64) {
        const int n = min(64, end - base);
        float    w   = 0.f;
        unsigned off = 0;
        if (lane < n) {
            const int c = col[base + lane];
            w   = vals[base + lane] * s_in[c];
            off = (unsigned)c << 8;          // c * 256 bytes
        }
        ldsw[wave][lane] = w;
        ldso[wave][lane] = off;
        #pragma unroll 4
        for (int j = 0; j < n; ++j) {
            const float    wj   = ldsw[wave][j];              // broadcast
            const unsigned voff = ldso[wave][j] + lane4;
            const unsigned int g = *(const unsigned int*)(q_in + voff);
            wsum += wj;
            ax += wj * (float)(g & 0xff);         ay += wj * (float)((g >> 8) & 0xff);
            az += wj * (float)((g >> 16) & 0xff); aw += wj * (float)(g >> 24);
        }
    }

    const float bias = 128.0f * wsum;   // wsum already uniform
    const float px = ax - bias, py = ay - bias, pz = az - bias, pw = aw - bias;

    float s = px * px + py * py + pz * pz + pw * pw;
    #pragma unroll
    for (int off = 32; off; off >>= 1) s += __shfl_xor(s, off);

    const float sc = 1.0f / fmaxf(sqrtf(s), EPS);
    const float hx = px * sc, hy = py * sc, hz = pz * sc, hw = pw * sc;

    const long idx = (long)r * 64 + lane;

    float m = fmaxf(fmaxf(fabsf(hx), fabsf(hy)), fmaxf(fabsf(hz), fabsf(hw)));
    #pragma unroll
    for (int off = 32; off; off >>= 1) m = fmaxf(m, __shfl_xor(m, off));
    const float mg  = fmaxf(m, 1e-30f);
    const float inv = 127.0f / mg;
    const unsigned int u0 = (unsigned int)(int)rintf(fmaf(hx, inv, 128.0f));
    const unsigned int u1 = (unsigned int)(int)rintf(fmaf(hy, inv, 128.0f));
    const unsigned int u2 = (unsigned int)(int)rintf(fmaf(hz, inv, 128.0f));
    const unsigned int u3 = (unsigned int)(int)rintf(fmaf(hw, inv, 128.0f));
    ((unsigned int*)q_out)[idx] = u0 | (u1 << 8) | (u2 << 16) | (u3 << 24);
    if (lane == 0) s_out[r] = mg * (1.0f / 127.0f);

    const float inv4 = 7.0f / mg;
    const unsigned int n0 = ((unsigned int)((int)rintf(hx * inv4) + 8)) & 15u;
    const unsigned int n1 = ((unsigned int)((int)rintf(hy * inv4) + 8)) & 15u;
    const unsigned int n2 = ((unsigned int)((int)rintf(hz * inv4) + 8)) & 15u;
    const unsigned int n3 = ((unsigned int)((int)rintf(hw * inv4) + 8)) & 15u;
    q4_out[idx] = (unsigned short)(n0 | (n1 << 4) | (n2 << 8) | (n3 << 12));
    if (lane == 0) s4_out[r] = mg * (1.0f / 7.0f);
}

// L1/L2: SpMM over packed-int4 table (2B/lane), LDS-broadcast metadata,
// byte-cvt mixed-sum decode:
//   SA=sum w*(n0+16n1), SB=sum w*(n1+16n2), SC=sum w*(n2+16n3), SD=sum w*n3
//   A3=SD, A2=SC-16A3, A1=SB-16A2, A0=SA-16A1 (exact).
// mode 0/1: + normalize + write int8 and int4 h tables
// mode 2:   + normalize + combine: out = 0.25*(dq(q0)+dq(q1)+dq(q2)+h)
__global__ __launch_bounds__(256) void spmm_q4_kernel(
    const unsigned char* __restrict__ q4_in,   // packed int4 rows, 128B stride
    const float* __restrict__ s4_in,
    const float* __restrict__ vals,
    const int*   __restrict__ col,
    const int*   __restrict__ row_ptr,
    unsigned char* __restrict__ q_out,
    float* __restrict__ s_out,
    unsigned short* __restrict__ q4_out,
    float* __restrict__ s4_out,
    const unsigned char* __restrict__ q0p, const float* __restrict__ s0p,
    const unsigned char* __restrict__ q1p, const float* __restrict__ s1p,
    const unsigned char* __restrict__ q2p, const float* __restrict__ s2p,
    float* __restrict__ out,
    int n_nodes, int mode)
{
    __shared__ float    ldsw[4][64];
    __shared__ unsigned ldso[4][64];

    const int wave = threadIdx.x >> 6, lane = threadIdx.x & 63;
    const int r = blockIdx.x * 4 + wave;
    if (r >= n_nodes) return;

    const int start = row_ptr[r];
    const int end   = row_ptr[r + 1];
    const unsigned lane2 = (unsigned)lane * 2u;

    float sa = 0.f, sb = 0.f, sc4 = 0.f, sd = 0.f;
    float wsum = 0.f;   // wave-uniform

    for (int base = start; base < end; base += 64) {
        const int n = min(64, end - base);
        float    w   = 0.f;
        unsigned off = 0;
        if (lane < n) {
            const int c = col[base + lane];
            w   = vals[base + lane] * s4_in[c];
            off = (unsigned)c << 7;          // c * 128 bytes
        }
        ldsw[wave][lane] = w;
        ldso[wave][lane] = off;
        #pragma unroll 4
        for (int j = 0; j < n; ++j) {
            const float    wj   = ldsw[wave][j];              // broadcast
            const unsigned voff = ldso[wave][j] + lane2;
            const unsigned int g = *(const unsigned short*)(q4_in + voff);
            wsum += wj;
            sa  += wj * (float)(g & 0xffu);
            sb  += wj * (float)((g >> 4) & 0xffu);
            sc4 += wj * (float)((g >> 8) & 0xffu);
            sd  += wj * (float)(g >> 12);
        }
    }

    // separate the mixed accumulators (exact)
    const float a3 = sd;
    const float a2 = sc4 - 16.0f * a3;
    const float a1 = sb  - 16.0f * a2;
    const float a0 = sa  - 16.0f * a1;

    const float bias = 8.0f * wsum;   // int4 bias center, wsum uniform

    const float px = a0 - bias, py = a1 - bias, pz = a2 - bias, pw = a3 - bias;

    float s = px * px + py * py + pz * pz + pw * pw;
    #pragma unroll
    for (int off = 32; off; off >>= 1) s += __shfl_xor(s, off);

    const float sc = 1.0f / fmaxf(sqrtf(s), EPS);
    const float hx = px * sc, hy = py * sc, hz = pz * sc, hw = pw * sc;

    const long idx = (long)r * 64 + lane;

    if (mode < 2) {
        float m = fmaxf(fmaxf(fabsf(hx), fabsf(hy)), fmaxf(fabsf(hz), fabsf(hw)));
        #pragma unroll
        for (int off = 32; off; off >>= 1) m = fmaxf(m, __shfl_xor(m, off));
        const float mg  = fmaxf(m, 1e-30f);
        const float inv = 127.0f / mg;
        const unsigned int u0 = (unsigned int)(int)rintf(fmaf(hx, inv, 128.0f));
        const unsigned int u1 = (unsigned int)(int)rintf(fmaf(hy, inv, 128.0f));
        const unsigned int u2 = (unsigned int)(int)rintf(fmaf(hz, inv, 128.0f));
        const unsigned int u3 = (unsigned int)(int)rintf(fmaf(hw, inv, 128.0f));
        ((unsigned int*)q_out)[idx] = u0 | (u1 << 8) | (u2 << 16) | (u3 << 24);
        if (lane == 0) s_out[r] = mg * (1.0f / 127.0f);

        const float inv4 = 7.0f / mg;
        const unsigned int n0 = ((unsigned int)((int)rintf(hx * inv4) + 8)) & 15u;
        const unsigned int n1 = ((unsigned int)((int)rintf(hy * inv4) + 8)) & 15u;
        const unsigned int n2 = ((unsigned int)((int)rintf(hz * inv4) + 8)) & 15u;
        const unsigned int n3 = ((unsigned int)((int)rintf(hw * inv4) + 8)) & 15u;
        q4_out[idx] = (unsigned short)(n0 | (n1 << 4) | (n2 << 8) | (n3 << 12));
        if (lane == 0) s4_out[r] = mg * (1.0f / 7.0f);
    } else {
        const unsigned int g0 = ((const unsigned int*)q0p)[idx];
        const unsigned int g1 = ((const unsigned int*)q1p)[idx];
        const unsigned int g2 = ((const unsigned int*)q2p)[idx];
        const float sc0 = s0p[r], sc1 = s1p[r], sc2 = s2p[r];
        float4 o;
        o.x = 0.25f * (((float)(g0 & 0xff)         - 128.f) * sc0
                     + ((float)(g1 & 0xff)         - 128.f) * sc1
                     + ((float)(g2 & 0xff)         - 128.f) * sc2 + hx);
        o.y = 0.25f * (((float)((g0 >> 8) & 0xff)  - 128.f) * sc0
                     + ((float)((g1 >> 8) & 0xff)  - 128.f) * sc1
                     + ((float)((g2 >> 8) & 0xff)  - 128.f) * sc2 + hy);
        o.z = 0.25f * (((float)((g0 >> 16) & 0xff) - 128.f) * sc0
                     + ((float)((g1 >> 16) & 0xff) - 128.f) * sc1
                     + ((float)((g2 >> 16) & 0xff) - 128.f) * sc2 + hz);
        o.w = 0.25f * (((float)(g0 >> 24)          - 128.f) * sc0
                     + ((float)(g1 >> 24)          - 128.f) * sc1
                     + ((float)(g2 >> 24)          - 128.f) * sc2 + hw);
        ((float4*)out)[idx] = o;
    }
}

extern "C" void kernel_launch(void* const* d_in, const int* in_sizes, int n_in,
                              void* d_out, int out_size, void* d_ws, size_t ws_size,
                              hipStream_t stream) {
    const float* x    = (const float*)d_in[0];
    const float* vals = (const float*)d_in[1];
    const int*   row  = (const int*)d_in[2];
    const int*   col  = (const int*)d_in[3];
    float* out = (float*)d_out;

    const int N = in_sizes[0] / D_FEAT;   // 100000
    const int E = in_sizes[1];            // 1600000

    // workspace: row_ptr | xq | sx | q1 | s1 | q2 | s2 | q1n | s1n | q2n | s2n
    auto align1k = [](size_t v) { return (v + 1023) & ~(size_t)1023; };
    const size_t rp_bytes = align1k((size_t)(N + 1) * sizeof(int));
    const size_t qbytes   = align1k((size_t)N * D_FEAT);               // int8 rows
    const size_t q4bytes  = align1k((size_t)N * D_FEAT / 2);           // int4 rows
    const size_t sbytes   = align1k((size_t)N * sizeof(float));
    char* ws = (char*)d_ws;
    int*            row_ptr = (int*)ws;            ws += rp_bytes;
    unsigned char*  xq  = (unsigned char*)ws;      ws += qbytes;
    float*          sx  = (float*)ws;              ws += sbytes;
    unsigned char*  q1  = (unsigned char*)ws;      ws += qbytes;
    float*          s1  = (float*)ws;              ws += sbytes;
    unsigned char*  q2  = (unsigned char*)ws;      ws += qbytes;
    float*          s2  = (float*)ws;              ws += sbytes;
    unsigned char*  q1n = (unsigned char*)ws;      ws += q4bytes;
    float*          s1n = (float*)ws;              ws += sbytes;
    unsigned char*  q2n = (unsigned char*)ws;      ws += q4bytes;
    float*          s2n = (float*)ws;

    // 1. CSR offsets
    {
        const int threads = 256;
        const int blocks = (E + 1 + threads - 1) / threads;
        build_row_ptr_kernel<<<blocks, threads, 0, stream>>>(row, row_ptr, E, N);
    }

    const int blocks = (N + 3) / 4;  // one wave per row, 4 waves per block

    // 2. quantize x (layer-0 int8 gather table + combine term)
    quant_rows_kernel<<<blocks, 256, 0, stream>>>(x, xq, sx, N);

    // 3. three fused layers
    // L0 (int8 gather): h1 -> q1/s1 (int8) + q1n/s1n (int4)
    spmm_q_kernel<<<blocks, 256, 0, stream>>>(xq, sx, vals, col, row_ptr,
                                              q1, s1, (unsigned short*)q1n, s1n, N);
    // L1 (int4 gather): h2 -> q2/s2 (int8) + q2n/s2n (int4)
    spmm_q4_kernel<<<blocks, 256, 0, stream>>>(q1n, s1n, vals, col, row_ptr,
                                               q2, s2, (unsigned short*)q2n, s2n,
                                               xq, sx, q1, s1, q2, s2, out, N, 0);
    // L2 (int4 gather + combine): out = 0.25*(x + h1 + h2 + h3)
    spmm_q4_kernel<<<blocks, 256, 0, stream>>>(q2n, s2n, vals, col, row_ptr,
                                               q2, s2, (unsigned short*)q2n, s2n,
                                               xq, sx, q1, s1, q2, s2, out, N, 2);
}